// Round 20
// baseline (698.316 us; speedup 1.0000x reference)
//
#include <hip/hip_runtime.h>
#include <hip/hip_bf16.h>

// TensorConvLayer: edge MLP (bf16 MFMA) -> tensor product (in-register) ->
// ticketed sorted-row emit (1 int atomic/edge) -> coalesced node gather -> BN.
//
// R19 -> R20: unroll-2 ILP failed (411us, VGPR DOWN to 52 -- compiler
// defeats source pipelining). Change the work/load ratio instead: each wave
// batches 2 edge-groups (32 edges), one pass through W2 serves both (load
// a0/a1/bv once -> 4 MFMAs -> 2 TP accumulations; the proven R10-R12 eA/eB
// pattern). Per-edge weight-load latency halves. LDS 26.6->52KB (~3 blk/CU),
// VGPR ~95 natural (no caps -- caps miscompile, R3/R4/R11). Aux chain
// byte-identical to green R18/R19.

typedef __bf16 bf16_t;
typedef bf16_t bf16x8 __attribute__((ext_vector_type(8)));
typedef bf16_t bf16x4 __attribute__((ext_vector_type(4)));
typedef float  f32x4  __attribute__((ext_vector_type(4)));

#define NREP 32   // stats replicas

__device__ __forceinline__ bf16_t f2bf(float f) {
  unsigned u = __builtin_bit_cast(unsigned, f);
  u += 0x7fffu + ((u >> 16) & 1u);          // round-to-nearest-even
  unsigned short s = (unsigned short)(u >> 16);
  return __builtin_bit_cast(bf16_t, s);
}

#define MFMA16(a, b, c) __builtin_amdgcn_mfma_f32_16x16x32_bf16((a), (b), (c), 0, 0, 0)

// ---------------------------------------------------------------- zero ----
__global__ __launch_bounds__(256) void tcl_zero(
    int* __restrict__ cnt, int* __restrict__ pos, float* __restrict__ statsrep,
    float* __restrict__ statsfin, int NN)
{
  int t = blockIdx.x * 256 + threadIdx.x;
  if (t < NN) { cnt[t] = 0; pos[t] = 0; }
  if (t < NREP * 64) statsrep[t] = 0.f;
  if (t < 64) statsfin[t] = 0.f;
}

// ------------------------------------------------------- count + wprep ----
__global__ __launch_bounds__(256) void tcl_count(
    const int* __restrict__ eidx, const float* __restrict__ w1,
    const float* __restrict__ w2, unsigned short* __restrict__ w1tg,
    unsigned short* __restrict__ w2tg, int* __restrict__ cnt, int E)
{
  int t = blockIdx.x * 256 + threadIdx.x;
  if (t < E) atomicAdd(&cnt[eidx[E + t]], 1);
  if (t < 64 * 64) {
    int k = t >> 6, n = t & 63;
    w1tg[n * 64 + k] = __builtin_bit_cast(unsigned short, f2bf(w1[t]));
  }
  if (t < 576 * 64) {
    int k = t / 576, n = t % 576;
    w2tg[n * 64 + k] = __builtin_bit_cast(unsigned short, f2bf(w2[t]));
  }
}

// ---------------------------------------------------------------- scan ----
__global__ __launch_bounds__(1024) void tcl_scan_a(
    const int* __restrict__ cnt, int* __restrict__ excl,
    int* __restrict__ bsum, int NN)
{
  __shared__ int sm[1024];
  int i = blockIdx.x * 1024 + threadIdx.x;
  int v = (i < NN) ? cnt[i] : 0;
  sm[threadIdx.x] = v;
  __syncthreads();
#pragma unroll
  for (int off = 1; off < 1024; off <<= 1) {
    int t = (threadIdx.x >= off) ? sm[threadIdx.x - off] : 0;
    __syncthreads();
    sm[threadIdx.x] += t;
    __syncthreads();
  }
  if (i < NN) excl[i] = sm[threadIdx.x] - v;
  if (threadIdx.x == 1023) bsum[blockIdx.x] = sm[threadIdx.x];
}

__global__ __launch_bounds__(128) void tcl_scan_b(int* __restrict__ bsum, int nb)
{
  __shared__ int sm[128];
  int t = threadIdx.x;
  int v = (t < nb) ? bsum[t] : 0;
  sm[t] = v;
  __syncthreads();
#pragma unroll
  for (int off = 1; off < 128; off <<= 1) {
    int u = (t >= off) ? sm[t - off] : 0;
    __syncthreads();
    sm[t] += u;
    __syncthreads();
  }
  if (t < nb) bsum[t] = sm[t] - v;
}

__global__ __launch_bounds__(256) void tcl_scan_c(
    const int* __restrict__ excl, const int* __restrict__ bsum,
    int* __restrict__ roff, int NN)
{
  int i = blockIdx.x * 256 + threadIdx.x;
  if (i < NN) roff[i] = excl[i] + bsum[i >> 10];
}

// ---------------------------------------------------------------- edge ----
// One wave = 32 edges (2 groups A/B of 16). lane = kg*16 + l15.
// SORTED: ticketed row write to tp. !SORTED: direct atomic scatter.
template <bool SORTED>
__global__ __launch_bounds__(256) void tcl_edge(
    const float* __restrict__ atom, const float* __restrict__ efeat,
    const float* __restrict__ esh, const int* __restrict__ eidx,
    const float* __restrict__ b1, const float* __restrict__ b2,
    const unsigned short* __restrict__ w1tg, const unsigned short* __restrict__ w2tg,
    float* __restrict__ outbuf, int* __restrict__ pos,
    const int* __restrict__ roff, int* __restrict__ cnt, int E)
{
  // wave-private LDS slices -> no __syncthreads anywhere. ~52KB/block.
  __shared__ __attribute__((aligned(16))) bf16_t hlds[4][2][16][72];
  __shared__ __attribute__((aligned(16))) float  xg[4][2][16][68];

  const int tid  = threadIdx.x;
  const int wv   = tid >> 6;      // wave 0..3 (independent)
  const int lane = tid & 63;
  const int l15  = lane & 15;     // edge in group
  const int kg   = lane >> 4;     // K-slice 0..3
  const int kh   = kg >> 1;
  const bf16_t* w1b = (const bf16_t*)w1tg;
  const bf16_t* w2b = (const bf16_t*)w2tg;

  const int npair = (E + 31) >> 5;
  const int gw0 = blockIdx.x * 4 + wv;
  const int gstride = gridDim.x * 4;

  for (int p = gw0; p < npair; p += gstride) {
    long geA = (long)p * 32 + l15;
    long geB = geA + 16;
    bool vA = geA < E, vB = geB < E;

    // ---- A: efeat -> B-fragments for both edges (8 float4 in flight) ----
    bf16x8 BfA0, BfA1, BfB0, BfB1;
    {
      float4 a = {0,0,0,0}, b = a, c = a, d = a, e = a, f = a, gq = a, h = a;
      if (vA) {
        const float4* pp = (const float4*)(efeat + geA * 64 + kg * 8);
        a = pp[0]; b = pp[1];
        const float4* q = (const float4*)(efeat + geA * 64 + 32 + kg * 8);
        c = q[0]; d = q[1];
      }
      if (vB) {
        const float4* pp = (const float4*)(efeat + geB * 64 + kg * 8);
        e = pp[0]; f = pp[1];
        const float4* q = (const float4*)(efeat + geB * 64 + 32 + kg * 8);
        gq = q[0]; h = q[1];
      }
      BfA0[0]=f2bf(a.x); BfA0[1]=f2bf(a.y); BfA0[2]=f2bf(a.z); BfA0[3]=f2bf(a.w);
      BfA0[4]=f2bf(b.x); BfA0[5]=f2bf(b.y); BfA0[6]=f2bf(b.z); BfA0[7]=f2bf(b.w);
      BfA1[0]=f2bf(c.x); BfA1[1]=f2bf(c.y); BfA1[2]=f2bf(c.z); BfA1[3]=f2bf(c.w);
      BfA1[4]=f2bf(d.x); BfA1[5]=f2bf(d.y); BfA1[6]=f2bf(d.z); BfA1[7]=f2bf(d.w);
      BfB0[0]=f2bf(e.x); BfB0[1]=f2bf(e.y); BfB0[2]=f2bf(e.z); BfB0[3]=f2bf(e.w);
      BfB0[4]=f2bf(f.x); BfB0[5]=f2bf(f.y); BfB0[6]=f2bf(f.z); BfB0[7]=f2bf(f.w);
      BfB1[0]=f2bf(gq.x); BfB1[1]=f2bf(gq.y); BfB1[2]=f2bf(gq.z); BfB1[3]=f2bf(gq.w);
      BfB1[4]=f2bf(h.x); BfB1[5]=f2bf(h.y); BfB1[6]=f2bf(h.z); BfB1[7]=f2bf(h.w);
    }

    // ---- B: premultiplied TP coefficient tables for both edges ----
    //  [0:16) x0 | [16:40) x1*sh0*c11 | [40:48) (x1.sh1)*c10
    //  [48:64) x0*sh0*c00 | [64:67) sh1*c01
#pragma unroll 2
    for (int gsel = 0; gsel < 2; ++gsel) {
      long ge = gsel ? geB : geA;
      if (ge < E) {
        int dst = eidx[ge];
        const float* xr = atom + (long)dst * 40;
        const float inv_s2 = 0.70710678118654752f;
        float* xgr = xg[wv][gsel][l15];
        if (kg == 0) {
          for (int i = 0; i < 16; ++i) xgr[i] = xr[i];
        } else if (kg == 1) {
          float k11 = esh[ge * 4] * inv_s2 * 0.35355339059327378f;
          for (int t2 = 0; t2 < 24; ++t2) xgr[16 + t2] = xr[16 + t2] * k11;
        } else if (kg == 2) {
          float s1x = esh[ge * 4 + 1], s1y = esh[ge * 4 + 2], s1z = esh[ge * 4 + 3];
          float k10 = inv_s2 * 0.20412414523193150f;
          for (int i = 0; i < 8; ++i) {
            float y = xr[16 + 3 * i] * s1x + xr[17 + 3 * i] * s1y + xr[18 + 3 * i] * s1z;
            xgr[40 + i] = y * k10;
          }
          float ks = inv_s2 * 0.25f;
          xgr[64] = s1x * ks;
          xgr[65] = s1y * ks;
          xgr[66] = s1z * ks;
        } else {
          float k0s = esh[ge * 4] * inv_s2 * 0.25f;
          for (int i = 0; i < 16; ++i) xgr[48 + i] = xr[i] * k0s;
        }
      }
    }

    // ---- C: GEMM1  h = relu(W1T . ef + b1) for both edges ----
    for (int mf = 0; mf < 4; ++mf) {
      const bf16_t* ap = w1b + (16 * mf + l15) * 64;
      bf16x8 a0 = *(const bf16x8*)(ap + kg * 8);
      bf16x8 a1 = *(const bf16x8*)(ap + 32 + kg * 8);
      f32x4 accA = {0.f, 0.f, 0.f, 0.f};
      f32x4 accB = {0.f, 0.f, 0.f, 0.f};
      accA = MFMA16(a0, BfA0, accA);
      accA = MFMA16(a1, BfA1, accA);
      accB = MFMA16(a0, BfB0, accB);
      accB = MFMA16(a1, BfB1, accB);
      int j0 = 16 * mf + 4 * kg;   // C/D: col=lane&15 (edge), row=(lane>>4)*4+r
      bf16x4 hvA, hvB;
#pragma unroll
      for (int r = 0; r < 4; ++r) {
        float xA = accA[r] + b1[j0 + r];
        float xB = accB[r] + b1[j0 + r];
        hvA[r] = f2bf(xA > 0.f ? xA : 0.f);
        hvB[r] = f2bf(xB > 0.f ? xB : 0.f);
      }
      *(bf16x4*)&hlds[wv][0][l15][j0] = hvA;
      *(bf16x4*)&hlds[wv][1][l15][j0] = hvB;
    }

    // ---- D: re-read h as B-fragments (same wave; lgkmcnt ordering) ----
    bf16x8 BhA0 = *(const bf16x8*)&hlds[wv][0][l15][kg * 8];
    bf16x8 BhA1 = *(const bf16x8*)&hlds[wv][0][l15][32 + kg * 8];
    bf16x8 BhB0 = *(const bf16x8*)&hlds[wv][1][l15][kg * 8];
    bf16x8 BhB1 = *(const bf16x8*)&hlds[wv][1][l15][32 + kg * 8];
    float sA0 = xg[wv][0][l15][64], sA1 = xg[wv][0][l15][65], sA2 = xg[wv][0][l15][66];
    float sB0 = xg[wv][1][l15][64], sB1 = xg[wv][1][l15][65], sB2 = xg[wv][1][l15][66];

    // ---- E: GEMM2 + TP; one weight pass serves both edges ----
    float o0A[4] = {}, o0B[4] = {};
    float o1A[4][3] = {}, o1B[4][3] = {};

    for (int mf = 0; mf < 16; ++mf) {          // w00: i=mf, j=4*kg+r
      const bf16_t* ap = w2b + (16 * mf + l15) * 64;
      bf16x8 a0 = *(const bf16x8*)(ap + kg * 8);
      bf16x8 a1 = *(const bf16x8*)(ap + 32 + kg * 8);
      f32x4 bv = *(const f32x4*)&b2[16 * mf + 4 * kg];
      f32x4 accA = {0.f, 0.f, 0.f, 0.f};
      f32x4 accB = {0.f, 0.f, 0.f, 0.f};
      accA = MFMA16(a0, BhA0, accA);
      accA = MFMA16(a1, BhA1, accA);
      accB = MFMA16(a0, BhB0, accB);
      accB = MFMA16(a1, BhB1, accB);
      float cA = xg[wv][0][l15][48 + mf], cB = xg[wv][1][l15][48 + mf];
#pragma unroll
      for (int r = 0; r < 4; ++r) {
        o0A[r] += (accA[r] + bv[r]) * cA;
        o0B[r] += (accB[r] + bv[r]) * cB;
      }
    }
    for (int mf = 16; mf < 20; ++mf) {         // w11: i=2*(mf-16)+kh, j=4*(kg&1)+r
      const bf16_t* ap = w2b + (16 * mf + l15) * 64;
      bf16x8 a0 = *(const bf16x8*)(ap + kg * 8);
      bf16x8 a1 = *(const bf16x8*)(ap + 32 + kg * 8);
      f32x4 bv = *(const f32x4*)&b2[16 * mf + 4 * kg];
      f32x4 accA = {0.f, 0.f, 0.f, 0.f};
      f32x4 accB = {0.f, 0.f, 0.f, 0.f};
      accA = MFMA16(a0, BhA0, accA);
      accA = MFMA16(a1, BhA1, accA);
      accB = MFMA16(a0, BhB0, accB);
      accB = MFMA16(a1, BhB1, accB);
      int i = 2 * (mf - 16) + kh;
      float cA0 = xg[wv][0][l15][16 + 3 * i], cA1 = xg[wv][0][l15][17 + 3 * i], cA2 = xg[wv][0][l15][18 + 3 * i];
      float cB0 = xg[wv][1][l15][16 + 3 * i], cB1 = xg[wv][1][l15][17 + 3 * i], cB2 = xg[wv][1][l15][18 + 3 * i];
#pragma unroll
      for (int r = 0; r < 4; ++r) {
        float wA = accA[r] + bv[r], wB = accB[r] + bv[r];
        o1A[r][0] += wA * cA0; o1A[r][1] += wA * cA1; o1A[r][2] += wA * cA2;
        o1B[r][0] += wB * cB0; o1B[r][1] += wB * cB1; o1B[r][2] += wB * cB2;
      }
    }
    for (int mf = 20; mf < 28; ++mf) {         // w01: i=2*(mf-20)+kh, j=4*(kg&1)+r
      const bf16_t* ap = w2b + (16 * mf + l15) * 64;
      bf16x8 a0 = *(const bf16x8*)(ap + kg * 8);
      bf16x8 a1 = *(const bf16x8*)(ap + 32 + kg * 8);
      f32x4 bv = *(const f32x4*)&b2[16 * mf + 4 * kg];
      f32x4 accA = {0.f, 0.f, 0.f, 0.f};
      f32x4 accB = {0.f, 0.f, 0.f, 0.f};
      accA = MFMA16(a0, BhA0, accA);
      accA = MFMA16(a1, BhA1, accA);
      accB = MFMA16(a0, BhB0, accB);
      accB = MFMA16(a1, BhB1, accB);
      int i = 2 * (mf - 20) + kh;
      float xA = xg[wv][0][l15][i], xB = xg[wv][1][l15][i];
#pragma unroll
      for (int r = 0; r < 4; ++r) {
        float tA = (accA[r] + bv[r]) * xA;
        float tB = (accB[r] + bv[r]) * xB;
        o1A[r][0] += tA * sA0; o1A[r][1] += tA * sA1; o1A[r][2] += tA * sA2;
        o1B[r][0] += tB * sB0; o1B[r][1] += tB * sB1; o1B[r][2] += tB * sB2;
      }
    }
    for (int mf = 28; mf < 36; ++mf) {         // w10: i=mf-28, j=4*kg+r
      const bf16_t* ap = w2b + (16 * mf + l15) * 64;
      bf16x8 a0 = *(const bf16x8*)(ap + kg * 8);
      bf16x8 a1 = *(const bf16x8*)(ap + 32 + kg * 8);
      f32x4 bv = *(const f32x4*)&b2[16 * mf + 4 * kg];
      f32x4 accA = {0.f, 0.f, 0.f, 0.f};
      f32x4 accB = {0.f, 0.f, 0.f, 0.f};
      accA = MFMA16(a0, BhA0, accA);
      accA = MFMA16(a1, BhA1, accA);
      accB = MFMA16(a0, BhB0, accB);
      accB = MFMA16(a1, BhB1, accB);
      float cA = xg[wv][0][l15][40 + mf - 28], cB = xg[wv][1][l15][40 + mf - 28];
#pragma unroll
      for (int r = 0; r < 4; ++r) {
        o0A[r] += (accA[r] + bv[r]) * cA;
        o0B[r] += (accB[r] + bv[r]) * cB;
      }
    }

    // fold kh pairs (lane^32: kg<->kg^2, same l15); lanes kg<2 hold full o1
    float o1fA[4][3], o1fB[4][3];
#pragma unroll
    for (int r = 0; r < 4; ++r)
#pragma unroll
      for (int c = 0; c < 3; ++c) {
        o1fA[r][c] = o1A[r][c] + __shfl_xor(o1A[r][c], 32);
        o1fB[r][c] = o1B[r][c] + __shfl_xor(o1B[r][c], 32);
      }

    // ---- F: emit both edges ----
    if (SORTED) {
      int dstA = 0, dstB = 0;
      if (kg == 0) {
        if (vA) dstA = roff[eidx[E + geA]] + atomicAdd(&pos[eidx[E + geA]], 1);
        if (vB) dstB = roff[eidx[E + geB]] + atomicAdd(&pos[eidx[E + geB]], 1);
      }
      dstA = __shfl(dstA, l15);
      dstB = __shfl(dstB, l15);
#pragma unroll 2
      for (int gsel = 0; gsel < 2; ++gsel) {
        bool vv = gsel ? vB : vA;
        if (!vv) continue;
        int dstrow = gsel ? dstB : dstA;
        float* o0p = gsel ? o0B : o0A;
        float (*o1p)[3] = gsel ? o1fB : o1fA;
        float* orow = outbuf + (long)dstrow * 40;
        f32x4 v0 = {o0p[0], o0p[1], o0p[2], o0p[3]};
        *(f32x4*)(orow + 4 * kg) = v0;
        if (kg < 2) {
          f32x4 u0 = {o1p[0][0], o1p[0][1], o1p[0][2], o1p[1][0]};
          f32x4 u1 = {o1p[1][1], o1p[1][2], o1p[2][0], o1p[2][1]};
          f32x4 u2 = {o1p[2][2], o1p[3][0], o1p[3][1], o1p[3][2]};
          float* ob = orow + 16 + 12 * kg;
          *(f32x4*)(ob + 0) = u0;
          *(f32x4*)(ob + 4) = u1;
          *(f32x4*)(ob + 8) = u2;
        }
      }
    } else {
#pragma unroll 2
      for (int gsel = 0; gsel < 2; ++gsel) {
        bool vv = gsel ? vB : vA;
        if (!vv) continue;
        long ge = gsel ? geB : geA;
        float* o0p = gsel ? o0B : o0A;
        float (*o1p)[3] = gsel ? o1fB : o1fA;
        int src = eidx[E + ge];
        float* srow = outbuf + (long)src * 40;
#pragma unroll
        for (int r = 0; r < 4; ++r) unsafeAtomicAdd(&srow[4 * kg + r], o0p[r]);
        if (kg < 2) {
          int j1 = 4 * kg;
#pragma unroll
          for (int r = 0; r < 4; ++r)
#pragma unroll
            for (int c = 0; c < 3; ++c)
              unsafeAtomicAdd(&srow[16 + 3 * (j1 + r) + c], o1p[r][c]);
        }
      }
    }
  }
}

// -------------------------------------------------------- node (gather) ----
// stats atomics striped over NREP replicas (contention /32) + in-wave 3:1
// vsq fold (8 atomics instead of 24 for v channels).
__global__ __launch_bounds__(256) void tcl_node2(
    const float* __restrict__ atom, const float* __restrict__ tp,
    const int* __restrict__ roff, const int* __restrict__ cnt,
    float* __restrict__ out, float* __restrict__ statsrep, int NN)
{
  int lane = threadIdx.x & 63;
  int gw = blockIdx.x * 4 + (threadIdx.x >> 6);
  int stride = gridDim.x * 4;
  float ssum = 0.f, ssq = 0.f, vsq = 0.f;
  for (int n = gw; n < NN; n += stride) {
    int deg = cnt[n];
    long base = roff[n];
    if (lane < 40) {
      float acc = 0.f;
      for (int d = 0; d < deg; ++d) acc += tp[(base + d) * 40 + lane];
      float c = deg > 0 ? (float)deg : 1.f;
      long idx = (long)n * 40 + lane;
      float o = acc / c + atom[idx];
      out[idx] = o;
      if (lane < 16) { ssum += o; ssq += o * o; }
      else           { vsq += o * o; }
    }
  }
  float* srep = statsrep + (long)(blockIdx.x & (NREP - 1)) * 64;
  // fold 3 vector components in-wave: lane 16+3m collects 16+3m+1, 16+3m+2
  float va = __shfl(vsq, lane + 1);
  float vb = __shfl(vsq, lane + 2);
  if (lane < 16) {
    unsafeAtomicAdd(&srep[lane], ssum);
    unsafeAtomicAdd(&srep[16 + lane], ssq);
  } else if (lane < 40 && (lane - 16) % 3 == 0) {
    unsafeAtomicAdd(&srep[32 + (lane - 16) / 3], (vsq + va) + vb);
  }
}

// ------------------------------------------------------------ collapse ----
__global__ __launch_bounds__(64) void tcl_collapse(
    const float* __restrict__ statsrep, float* __restrict__ statsfin)
{
  int c = threadIdx.x;
  float s = 0.f;
  for (int r = 0; r < NREP; ++r) s += statsrep[(long)r * 64 + c];
  statsfin[c] = s;
}

// ---------------------------------------------------- node (atomic path) ----
__global__ __launch_bounds__(256) void tcl_node(
    const float* __restrict__ atom, const int* __restrict__ cnt,
    float* __restrict__ out, float* __restrict__ stats, int NN)
{
  int lane = threadIdx.x & 63;
  int gw = blockIdx.x * 4 + (threadIdx.x >> 6);
  int stride = gridDim.x * 4;
  float ssum = 0.f, ssq = 0.f, vsq = 0.f;
  for (int r = gw; r < NN; r += stride) {
    float c = (float)cnt[r];
    c = c > 1.f ? c : 1.f;
    if (lane < 40) {
      long idx = (long)r * 40 + lane;
      float o = out[idx] / c + atom[idx];
      out[idx] = o;
      if (lane < 16) { ssum += o; ssq += o * o; }
      else           { vsq += o * o; }
    }
  }
  if (lane < 16) {
    unsafeAtomicAdd(&stats[lane], ssum);
    unsafeAtomicAdd(&stats[16 + lane], ssq);
  } else if (lane < 40) {
    unsafeAtomicAdd(&stats[32 + (lane - 16) / 3], vsq);
  }
}

// ---------------------------------------------------------------- norm ----
__global__ __launch_bounds__(256) void tcl_norm(
    float* __restrict__ out, const float* __restrict__ stats,
    const float* __restrict__ bnw, const float* __restrict__ bnb, int NN)
{
  long idx = (long)blockIdx.x * 256 + threadIdx.x;
  long tot = (long)NN * 40;
  if (idx >= tot) return;
  int c = (int)(idx % 40);
  float o = out[idx];
  float invN = 1.0f / (float)NN;
  if (c < 16) {
    float mean = stats[c] * invN;
    float var  = stats[16 + c] * invN - mean * mean;
    float rs   = rsqrtf(var + 1e-5f);
    o = (o - mean) * rs * bnw[c] + bnb[c];
  } else {
    int m = (c - 16) / 3;
    float vn = stats[32 + m] * invN * (1.0f / 3.0f);
    float rs = rsqrtf(vn + 1e-5f);
    o = o * rs * bnw[16 + m];
  }
  out[idx] = o;
}

// -------------------------------------------------------------- launch ----
extern "C" void kernel_launch(void* const* d_in, const int* in_sizes, int n_in,
                              void* d_out, int out_size, void* d_ws, size_t ws_size,
                              hipStream_t stream)
{
  const float* atom  = (const float*)d_in[0];
  const float* efeat = (const float*)d_in[1];
  const float* esh   = (const float*)d_in[2];
  const int*   eidx  = (const int*)d_in[3];
  const float* w1    = (const float*)d_in[4];
  const float* b1    = (const float*)d_in[5];
  const float* w2    = (const float*)d_in[6];
  const float* b2    = (const float*)d_in[7];
  const float* bnw   = (const float*)d_in[8];
  const float* bnb   = (const float*)d_in[9];
  int E  = in_sizes[3] / 2;
  int NN = in_sizes[0] / 40;
  float* out = (float*)d_out;

  // workspace layout (~81.7MB for E=500k, NN=100k; proven fit in R2/R17)
  size_t off = 0;
  auto align256 = [&](size_t o) { return (o + 255) & ~(size_t)255; };
  int* cnt = (int*)d_ws;                                   off += (size_t)NN * 4;
  off = align256(off);
  int* pos = (int*)((char*)d_ws + off);                    off += (size_t)NN * 4;
  off = align256(off);
  int* excl = (int*)((char*)d_ws + off);                   off += (size_t)NN * 4;
  off = align256(off);
  int* bsum = (int*)((char*)d_ws + off);                   off += 128 * 4;
  off = align256(off);
  int* roff = (int*)((char*)d_ws + off);                   off += (size_t)NN * 4;
  off = align256(off);
  float* statsrep = (float*)((char*)d_ws + off);           off += (size_t)NREP * 64 * 4;
  off = align256(off);
  float* statsfin = (float*)((char*)d_ws + off);           off += 64 * 4;
  off = align256(off);
  unsigned short* w1tg = (unsigned short*)((char*)d_ws + off); off += 64 * 64 * 2;
  off = align256(off);
  unsigned short* w2tg = (unsigned short*)((char*)d_ws + off); off += 576 * 64 * 2;
  off = align256(off);
  float* tp = (float*)((char*)d_ws + off);
  size_t need = off + (size_t)E * 40 * 4;

  int nb = (NN + 1023) / 1024;   // scan chunks (<=128)
  bool sorted = (ws_size >= need) && (nb <= 128);

  tcl_zero<<<(NN + 255) / 256, 256, 0, stream>>>(cnt, pos, statsrep, statsfin, NN);
  tcl_count<<<(E + 255) / 256, 256, 0, stream>>>(eidx, w1, w2, w1tg, w2tg, cnt, E);

  if (sorted) {
    tcl_scan_a<<<nb, 1024, 0, stream>>>(cnt, excl, bsum, NN);
    tcl_scan_b<<<1, 128, 0, stream>>>(bsum, nb);
    tcl_scan_c<<<(NN + 255) / 256, 256, 0, stream>>>(excl, bsum, roff, NN);
    tcl_edge<true><<<2048, 256, 0, stream>>>(atom, efeat, esh, eidx, b1, b2,
                                             w1tg, w2tg, tp, pos, roff, cnt, E);
    tcl_node2<<<1024, 256, 0, stream>>>(atom, tp, roff, cnt, out, statsrep, NN);
    tcl_collapse<<<1, 64, 0, stream>>>(statsrep, statsfin);
  } else {
    hipMemsetAsync(d_out, 0, (size_t)NN * 40 * sizeof(float), stream);
    tcl_edge<false><<<2048, 256, 0, stream>>>(atom, efeat, esh, eidx, b1, b2,
                                              w1tg, w2tg, out, pos, roff, cnt, E);
    tcl_node<<<256, 256, 0, stream>>>(atom, cnt, out, statsfin, NN);
  }
  tcl_norm<<<(int)(((long)NN * 40 + 255) / 256), 256, 0, stream>>>(out, statsfin, bnw, bnb, NN);
}

// Round 21
// 302.754 us; speedup vs baseline: 2.3065x; 2.3065x over previous
//
#include <hip/hip_runtime.h>
#include <hip/hip_bf16.h>

// TensorConvLayer: edge MLP (bf16 MFMA) -> tensor product (in-register) ->
// ticketed sorted-row emit (1 int atomic/edge) -> coalesced node gather -> BN.
//
// R20 -> R21: R20's 2-edge register batch spilled (VGPR 256, +700MB scratch
// traffic, 610us). Both ILP avenues dead (pragma: compiler tightens; batch:
// spills). New diagnosis of the 411us floor: phase E sweeps 73.7KB of W2
// cyclically -> thrashes 32KB L1 -> every weight load is a ~200cy L2 trip,
// unhidden (8360cy/group ~= 40 loads x 200cy). Fix the TIER: stage W1/W2/
// biases in LDS once per block (stride-144B rows -> 2-way conflicts = free),
// keep the wave-autonomous structure (8 waves/block, ONE barrier after
// staging, not R2's 4/tile). LDS 148KB -> 1 blk/CU. Aux chain = green R19.

typedef __bf16 bf16_t;
typedef bf16_t bf16x8 __attribute__((ext_vector_type(8)));
typedef bf16_t bf16x4 __attribute__((ext_vector_type(4)));
typedef float  f32x4  __attribute__((ext_vector_type(4)));

#define NREP 32   // stats replicas

__device__ __forceinline__ bf16_t f2bf(float f) {
  unsigned u = __builtin_bit_cast(unsigned, f);
  u += 0x7fffu + ((u >> 16) & 1u);          // round-to-nearest-even
  unsigned short s = (unsigned short)(u >> 16);
  return __builtin_bit_cast(bf16_t, s);
}

#define MFMA16(a, b, c) __builtin_amdgcn_mfma_f32_16x16x32_bf16((a), (b), (c), 0, 0, 0)

// ---------------------------------------------------------------- zero ----
__global__ __launch_bounds__(256) void tcl_zero(
    int* __restrict__ cnt, int* __restrict__ pos, float* __restrict__ statsrep,
    float* __restrict__ statsfin, int NN)
{
  int t = blockIdx.x * 256 + threadIdx.x;
  if (t < NN) { cnt[t] = 0; pos[t] = 0; }
  if (t < NREP * 64) statsrep[t] = 0.f;
  if (t < 64) statsfin[t] = 0.f;
}

// ------------------------------------------------------- count + wprep ----
__global__ __launch_bounds__(256) void tcl_count(
    const int* __restrict__ eidx, const float* __restrict__ w1,
    const float* __restrict__ w2, unsigned short* __restrict__ w1tg,
    unsigned short* __restrict__ w2tg, int* __restrict__ cnt, int E)
{
  int t = blockIdx.x * 256 + threadIdx.x;
  if (t < E) atomicAdd(&cnt[eidx[E + t]], 1);
  if (t < 64 * 64) {
    int k = t >> 6, n = t & 63;
    w1tg[n * 64 + k] = __builtin_bit_cast(unsigned short, f2bf(w1[t]));
  }
  if (t < 576 * 64) {
    int k = t / 576, n = t % 576;
    w2tg[n * 64 + k] = __builtin_bit_cast(unsigned short, f2bf(w2[t]));
  }
}

// ---------------------------------------------------------------- scan ----
__global__ __launch_bounds__(1024) void tcl_scan_a(
    const int* __restrict__ cnt, int* __restrict__ excl,
    int* __restrict__ bsum, int NN)
{
  __shared__ int sm[1024];
  int i = blockIdx.x * 1024 + threadIdx.x;
  int v = (i < NN) ? cnt[i] : 0;
  sm[threadIdx.x] = v;
  __syncthreads();
#pragma unroll
  for (int off = 1; off < 1024; off <<= 1) {
    int t = (threadIdx.x >= off) ? sm[threadIdx.x - off] : 0;
    __syncthreads();
    sm[threadIdx.x] += t;
    __syncthreads();
  }
  if (i < NN) excl[i] = sm[threadIdx.x] - v;
  if (threadIdx.x == 1023) bsum[blockIdx.x] = sm[threadIdx.x];
}

__global__ __launch_bounds__(128) void tcl_scan_b(int* __restrict__ bsum, int nb)
{
  __shared__ int sm[128];
  int t = threadIdx.x;
  int v = (t < nb) ? bsum[t] : 0;
  sm[t] = v;
  __syncthreads();
#pragma unroll
  for (int off = 1; off < 128; off <<= 1) {
    int u = (t >= off) ? sm[t - off] : 0;
    __syncthreads();
    sm[t] += u;
    __syncthreads();
  }
  if (t < nb) bsum[t] = sm[t] - v;
}

__global__ __launch_bounds__(256) void tcl_scan_c(
    const int* __restrict__ excl, const int* __restrict__ bsum,
    int* __restrict__ roff, int NN)
{
  int i = blockIdx.x * 256 + threadIdx.x;
  if (i < NN) roff[i] = excl[i] + bsum[i >> 10];
}

// ---------------------------------------------------------------- edge ----
// 512 threads = 8 autonomous waves, 16 edges each. Weights staged in LDS
// once per block (single barrier); waves then loop groups independently.
// lane = kg*16 + l15.
template <bool SORTED>
__global__ __launch_bounds__(512) void tcl_edge(
    const float* __restrict__ atom, const float* __restrict__ efeat,
    const float* __restrict__ esh, const int* __restrict__ eidx,
    const float* __restrict__ b1, const float* __restrict__ b2,
    const unsigned short* __restrict__ w1tg, const unsigned short* __restrict__ w2tg,
    float* __restrict__ outbuf, int* __restrict__ pos,
    const int* __restrict__ roff, int* __restrict__ cnt, int E)
{
  // 148KB LDS -> 1 block/CU. Row stride 72 elems (144B) -> 2-way bank
  // conflicts on row-major reads (free, m136).
  __shared__ __attribute__((aligned(16))) bf16_t w2l[576][72];
  __shared__ __attribute__((aligned(16))) bf16_t w1l[64][72];
  __shared__ __attribute__((aligned(16))) float  b2l[576];
  __shared__ __attribute__((aligned(16))) float  b1l[64];
  __shared__ __attribute__((aligned(16))) bf16_t hlds[8][16][72];
  __shared__ __attribute__((aligned(16))) float  xg[8][16][68];

  const int tid  = threadIdx.x;
  const int wv   = tid >> 6;      // wave 0..7 (independent after staging)
  const int lane = tid & 63;
  const int l15  = lane & 15;     // edge in group
  const int kg   = lane >> 4;     // K-slice 0..3
  const int kh   = kg >> 1;

  // ---- stage weights once per block ----
  for (int i = tid; i < 576 * 64; i += 512)
    w2l[i >> 6][i & 63] = __builtin_bit_cast(bf16_t, w2tg[i]);
  for (int i = tid; i < 64 * 64; i += 512)
    w1l[i >> 6][i & 63] = __builtin_bit_cast(bf16_t, w1tg[i]);
  for (int i = tid; i < 576; i += 512) b2l[i] = b2[i];
  if (tid < 64) b1l[tid] = b1[tid];
  __syncthreads();                 // the ONLY barrier

  const int ngr = (E + 15) >> 4;
  const int gw0 = blockIdx.x * 8 + wv;
  const int gstride = gridDim.x * 8;

  for (int g = gw0; g < ngr; g += gstride) {
    long ge = (long)g * 16 + l15;
    bool v = ge < E;

    // ---- A: efeat -> B-fragments direct from global (full K=64 row) ----
    bf16x8 Bf0, Bf1;
    {
      float4 a = {0,0,0,0}, b = a, c = a, d = a;
      if (v) {
        const float4* p = (const float4*)(efeat + ge * 64 + kg * 8);
        a = p[0]; b = p[1];
        const float4* q = (const float4*)(efeat + ge * 64 + 32 + kg * 8);
        c = q[0]; d = q[1];
      }
      Bf0[0]=f2bf(a.x); Bf0[1]=f2bf(a.y); Bf0[2]=f2bf(a.z); Bf0[3]=f2bf(a.w);
      Bf0[4]=f2bf(b.x); Bf0[5]=f2bf(b.y); Bf0[6]=f2bf(b.z); Bf0[7]=f2bf(b.w);
      Bf1[0]=f2bf(c.x); Bf1[1]=f2bf(c.y); Bf1[2]=f2bf(c.z); Bf1[3]=f2bf(c.w);
      Bf1[4]=f2bf(d.x); Bf1[5]=f2bf(d.y); Bf1[6]=f2bf(d.z); Bf1[7]=f2bf(d.w);
    }

    // ---- B: premultiplied TP coefficient table (work split by kg) ----
    //  [0:16) x0 | [16:40) x1*sh0*c11 | [40:48) (x1.sh1)*c10
    //  [48:64) x0*sh0*c00 | [64:67) sh1*c01
    if (v) {
      int dst = eidx[ge];
      const float* xr = atom + (long)dst * 40;
      const float inv_s2 = 0.70710678118654752f;
      if (kg == 0) {
        for (int i = 0; i < 16; ++i) xg[wv][l15][i] = xr[i];
      } else if (kg == 1) {
        float k11 = esh[ge * 4] * inv_s2 * 0.35355339059327378f;
        for (int t2 = 0; t2 < 24; ++t2) xg[wv][l15][16 + t2] = xr[16 + t2] * k11;
      } else if (kg == 2) {
        float s1x = esh[ge * 4 + 1], s1y = esh[ge * 4 + 2], s1z = esh[ge * 4 + 3];
        float k10 = inv_s2 * 0.20412414523193150f;
        for (int i = 0; i < 8; ++i) {
          float y = xr[16 + 3 * i] * s1x + xr[17 + 3 * i] * s1y + xr[18 + 3 * i] * s1z;
          xg[wv][l15][40 + i] = y * k10;
        }
        float ks = inv_s2 * 0.25f;
        xg[wv][l15][64] = s1x * ks;
        xg[wv][l15][65] = s1y * ks;
        xg[wv][l15][66] = s1z * ks;
      } else {
        float k0s = esh[ge * 4] * inv_s2 * 0.25f;
        for (int i = 0; i < 16; ++i) xg[wv][l15][48 + i] = xr[i] * k0s;
      }
    }

    // ---- C: GEMM1  h = relu(W1T . ef + b1), weights from LDS ----
    for (int mf = 0; mf < 4; ++mf) {
      const bf16_t* ap = &w1l[16 * mf + l15][0];
      bf16x8 a0 = *(const bf16x8*)(ap + kg * 8);
      bf16x8 a1 = *(const bf16x8*)(ap + 32 + kg * 8);
      f32x4 acc = {0.f, 0.f, 0.f, 0.f};
      acc = MFMA16(a0, Bf0, acc);
      acc = MFMA16(a1, Bf1, acc);
      int j0 = 16 * mf + 4 * kg;   // C/D: col=lane&15 (edge), row=(lane>>4)*4+r
      bf16x4 hv;
#pragma unroll
      for (int r = 0; r < 4; ++r) {
        float x = acc[r] + b1l[j0 + r];
        x = x > 0.f ? x : 0.f;
        hv[r] = f2bf(x);
      }
      *(bf16x4*)&hlds[wv][l15][j0] = hv;
    }

    // ---- D: re-read h as B-fragments (same wave; lgkmcnt ordering) ----
    bf16x8 Bh0 = *(const bf16x8*)&hlds[wv][l15][kg * 8];
    bf16x8 Bh1 = *(const bf16x8*)&hlds[wv][l15][32 + kg * 8];
    float s0 = xg[wv][l15][64], s1 = xg[wv][l15][65], s2 = xg[wv][l15][66];

    // ---- E: GEMM2 + TP; weights from LDS (no L1/L2 on critical path) ----
    float o0[4] = {};        // out0 slice j = 4*kg + r (complete per lane)
    float o1[4][3] = {};     // out1 slice j = 4*(kg&1) + r (partial: this kh)

    for (int mf = 0; mf < 16; ++mf) {          // w00: i=mf, j=4*kg+r
      const bf16_t* ap = &w2l[16 * mf + l15][0];
      bf16x8 a0 = *(const bf16x8*)(ap + kg * 8);
      bf16x8 a1 = *(const bf16x8*)(ap + 32 + kg * 8);
      f32x4 bv = *(const f32x4*)&b2l[16 * mf + 4 * kg];
      f32x4 acc = {0.f, 0.f, 0.f, 0.f};
      acc = MFMA16(a0, Bh0, acc);
      acc = MFMA16(a1, Bh1, acc);
      float cA = xg[wv][l15][48 + mf];
#pragma unroll
      for (int r = 0; r < 4; ++r) o0[r] += (acc[r] + bv[r]) * cA;
    }
    for (int mf = 16; mf < 20; ++mf) {         // w11: i=2*(mf-16)+kh, j=4*(kg&1)+r
      const bf16_t* ap = &w2l[16 * mf + l15][0];
      bf16x8 a0 = *(const bf16x8*)(ap + kg * 8);
      bf16x8 a1 = *(const bf16x8*)(ap + 32 + kg * 8);
      f32x4 bv = *(const f32x4*)&b2l[16 * mf + 4 * kg];
      f32x4 acc = {0.f, 0.f, 0.f, 0.f};
      acc = MFMA16(a0, Bh0, acc);
      acc = MFMA16(a1, Bh1, acc);
      int i = 2 * (mf - 16) + kh;
      float c0 = xg[wv][l15][16 + 3 * i], c1 = xg[wv][l15][17 + 3 * i], c2 = xg[wv][l15][18 + 3 * i];
#pragma unroll
      for (int r = 0; r < 4; ++r) {
        float wA = acc[r] + bv[r];
        o1[r][0] += wA * c0; o1[r][1] += wA * c1; o1[r][2] += wA * c2;
      }
    }
    for (int mf = 20; mf < 28; ++mf) {         // w01: i=2*(mf-20)+kh, j=4*(kg&1)+r
      const bf16_t* ap = &w2l[16 * mf + l15][0];
      bf16x8 a0 = *(const bf16x8*)(ap + kg * 8);
      bf16x8 a1 = *(const bf16x8*)(ap + 32 + kg * 8);
      f32x4 bv = *(const f32x4*)&b2l[16 * mf + 4 * kg];
      f32x4 acc = {0.f, 0.f, 0.f, 0.f};
      acc = MFMA16(a0, Bh0, acc);
      acc = MFMA16(a1, Bh1, acc);
      int i = 2 * (mf - 20) + kh;
      float xA = xg[wv][l15][i];
#pragma unroll
      for (int r = 0; r < 4; ++r) {
        float tA = (acc[r] + bv[r]) * xA;
        o1[r][0] += tA * s0; o1[r][1] += tA * s1; o1[r][2] += tA * s2;
      }
    }
    for (int mf = 28; mf < 36; ++mf) {         // w10: i=mf-28, j=4*kg+r
      const bf16_t* ap = &w2l[16 * mf + l15][0];
      bf16x8 a0 = *(const bf16x8*)(ap + kg * 8);
      bf16x8 a1 = *(const bf16x8*)(ap + 32 + kg * 8);
      f32x4 bv = *(const f32x4*)&b2l[16 * mf + 4 * kg];
      f32x4 acc = {0.f, 0.f, 0.f, 0.f};
      acc = MFMA16(a0, Bh0, acc);
      acc = MFMA16(a1, Bh1, acc);
      float cA = xg[wv][l15][40 + mf - 28];
#pragma unroll
      for (int r = 0; r < 4; ++r) o0[r] += (acc[r] + bv[r]) * cA;
    }

    // fold kh pairs (lane^32: kg<->kg^2, same l15); lanes kg<2 hold full o1
    float o1f[4][3];
#pragma unroll
    for (int r = 0; r < 4; ++r)
#pragma unroll
      for (int c = 0; c < 3; ++c)
        o1f[r][c] = o1[r][c] + __shfl_xor(o1[r][c], 32);

    // ---- F: emit ----
    if (SORTED) {
      int dstrow = 0;
      if (v && kg == 0) {
        int src = eidx[E + ge];
        dstrow = roff[src] + atomicAdd(&pos[src], 1);
      }
      dstrow = __shfl(dstrow, l15);      // lane l15 holds kg==0's ticket
      if (v) {
        float* orow = outbuf + (long)dstrow * 40;
        f32x4 v0 = {o0[0], o0[1], o0[2], o0[3]};
        *(f32x4*)(orow + 4 * kg) = v0;
        if (kg < 2) {
          f32x4 u0 = {o1f[0][0], o1f[0][1], o1f[0][2], o1f[1][0]};
          f32x4 u1 = {o1f[1][1], o1f[1][2], o1f[2][0], o1f[2][1]};
          f32x4 u2 = {o1f[2][2], o1f[3][0], o1f[3][1], o1f[3][2]};
          float* ob = orow + 16 + 12 * kg;
          *(f32x4*)(ob + 0) = u0;
          *(f32x4*)(ob + 4) = u1;
          *(f32x4*)(ob + 8) = u2;
        }
      }
    } else {
      if (v) {
        int src = eidx[E + ge];
        float* srow = outbuf + (long)src * 40;
#pragma unroll
        for (int r = 0; r < 4; ++r) unsafeAtomicAdd(&srow[4 * kg + r], o0[r]);
        if (kg < 2) {
          int j1 = 4 * kg;
#pragma unroll
          for (int r = 0; r < 4; ++r)
#pragma unroll
            for (int c = 0; c < 3; ++c)
              unsafeAtomicAdd(&srow[16 + 3 * (j1 + r) + c], o1f[r][c]);
        }
      }
    }
  }
}

// -------------------------------------------------------- node (gather) ----
// stats atomics striped over NREP replicas (contention /32) + in-wave 3:1
// vsq fold (8 atomics instead of 24 for v channels).
__global__ __launch_bounds__(256) void tcl_node2(
    const float* __restrict__ atom, const float* __restrict__ tp,
    const int* __restrict__ roff, const int* __restrict__ cnt,
    float* __restrict__ out, float* __restrict__ statsrep, int NN)
{
  int lane = threadIdx.x & 63;
  int gw = blockIdx.x * 4 + (threadIdx.x >> 6);
  int stride = gridDim.x * 4;
  float ssum = 0.f, ssq = 0.f, vsq = 0.f;
  for (int n = gw; n < NN; n += stride) {
    int deg = cnt[n];
    long base = roff[n];
    if (lane < 40) {
      float acc = 0.f;
      for (int d = 0; d < deg; ++d) acc += tp[(base + d) * 40 + lane];
      float c = deg > 0 ? (float)deg : 1.f;
      long idx = (long)n * 40 + lane;
      float o = acc / c + atom[idx];
      out[idx] = o;
      if (lane < 16) { ssum += o; ssq += o * o; }
      else           { vsq += o * o; }
    }
  }
  float* srep = statsrep + (long)(blockIdx.x & (NREP - 1)) * 64;
  // fold 3 vector components in-wave: lane 16+3m collects 16+3m+1, 16+3m+2
  float va = __shfl(vsq, lane + 1);
  float vb = __shfl(vsq, lane + 2);
  if (lane < 16) {
    unsafeAtomicAdd(&srep[lane], ssum);
    unsafeAtomicAdd(&srep[16 + lane], ssq);
  } else if (lane < 40 && (lane - 16) % 3 == 0) {
    unsafeAtomicAdd(&srep[32 + (lane - 16) / 3], (vsq + va) + vb);
  }
}

// ------------------------------------------------------------ collapse ----
__global__ __launch_bounds__(64) void tcl_collapse(
    const float* __restrict__ statsrep, float* __restrict__ statsfin)
{
  int c = threadIdx.x;
  float s = 0.f;
  for (int r = 0; r < NREP; ++r) s += statsrep[(long)r * 64 + c];
  statsfin[c] = s;
}

// ---------------------------------------------------- node (atomic path) ----
__global__ __launch_bounds__(256) void tcl_node(
    const float* __restrict__ atom, const int* __restrict__ cnt,
    float* __restrict__ out, float* __restrict__ stats, int NN)
{
  int lane = threadIdx.x & 63;
  int gw = blockIdx.x * 4 + (threadIdx.x >> 6);
  int stride = gridDim.x * 4;
  float ssum = 0.f, ssq = 0.f, vsq = 0.f;
  for (int r = gw; r < NN; r += stride) {
    float c = (float)cnt[r];
    c = c > 1.f ? c : 1.f;
    if (lane < 40) {
      long idx = (long)r * 40 + lane;
      float o = out[idx] / c + atom[idx];
      out[idx] = o;
      if (lane < 16) { ssum += o; ssq += o * o; }
      else           { vsq += o * o; }
    }
  }
  if (lane < 16) {
    unsafeAtomicAdd(&stats[lane], ssum);
    unsafeAtomicAdd(&stats[16 + lane], ssq);
  } else if (lane < 40) {
    unsafeAtomicAdd(&stats[32 + (lane - 16) / 3], vsq);
  }
}

// ---------------------------------------------------------------- norm ----
__global__ __launch_bounds__(256) void tcl_norm(
    float* __restrict__ out, const float* __restrict__ stats,
    const float* __restrict__ bnw, const float* __restrict__ bnb, int NN)
{
  long idx = (long)blockIdx.x * 256 + threadIdx.x;
  long tot = (long)NN * 40;
  if (idx >= tot) return;
  int c = (int)(idx % 40);
  float o = out[idx];
  float invN = 1.0f / (float)NN;
  if (c < 16) {
    float mean = stats[c] * invN;
    float var  = stats[16 + c] * invN - mean * mean;
    float rs   = rsqrtf(var + 1e-5f);
    o = (o - mean) * rs * bnw[c] + bnb[c];
  } else {
    int m = (c - 16) / 3;
    float vn = stats[32 + m] * invN * (1.0f / 3.0f);
    float rs = rsqrtf(vn + 1e-5f);
    o = o * rs * bnw[16 + m];
  }
  out[idx] = o;
}

// -------------------------------------------------------------- launch ----
extern "C" void kernel_launch(void* const* d_in, const int* in_sizes, int n_in,
                              void* d_out, int out_size, void* d_ws, size_t ws_size,
                              hipStream_t stream)
{
  const float* atom  = (const float*)d_in[0];
  const float* efeat = (const float*)d_in[1];
  const float* esh   = (const float*)d_in[2];
  const int*   eidx  = (const int*)d_in[3];
  const float* w1    = (const float*)d_in[4];
  const float* b1    = (const float*)d_in[5];
  const float* w2    = (const float*)d_in[6];
  const float* b2    = (const float*)d_in[7];
  const float* bnw   = (const float*)d_in[8];
  const float* bnb   = (const float*)d_in[9];
  int E  = in_sizes[3] / 2;
  int NN = in_sizes[0] / 40;
  float* out = (float*)d_out;

  // workspace layout (~81.7MB for E=500k, NN=100k; proven fit in R2/R17)
  size_t off = 0;
  auto align256 = [&](size_t o) { return (o + 255) & ~(size_t)255; };
  int* cnt = (int*)d_ws;                                   off += (size_t)NN * 4;
  off = align256(off);
  int* pos = (int*)((char*)d_ws + off);                    off += (size_t)NN * 4;
  off = align256(off);
  int* excl = (int*)((char*)d_ws + off);                   off += (size_t)NN * 4;
  off = align256(off);
  int* bsum = (int*)((char*)d_ws + off);                   off += 128 * 4;
  off = align256(off);
  int* roff = (int*)((char*)d_ws + off);                   off += (size_t)NN * 4;
  off = align256(off);
  float* statsrep = (float*)((char*)d_ws + off);           off += (size_t)NREP * 64 * 4;
  off = align256(off);
  float* statsfin = (float*)((char*)d_ws + off);           off += 64 * 4;
  off = align256(off);
  unsigned short* w1tg = (unsigned short*)((char*)d_ws + off); off += 64 * 64 * 2;
  off = align256(off);
  unsigned short* w2tg = (unsigned short*)((char*)d_ws + off); off += 576 * 64 * 2;
  off = align256(off);
  float* tp = (float*)((char*)d_ws + off);
  size_t need = off + (size_t)E * 40 * 4;

  int nb = (NN + 1023) / 1024;   // scan chunks (<=128)
  bool sorted = (ws_size >= need) && (nb <= 128);

  tcl_zero<<<(NN + 255) / 256, 256, 0, stream>>>(cnt, pos, statsrep, statsfin, NN);
  tcl_count<<<(E + 255) / 256, 256, 0, stream>>>(eidx, w1, w2, w1tg, w2tg, cnt, E);

  if (sorted) {
    tcl_scan_a<<<nb, 1024, 0, stream>>>(cnt, excl, bsum, NN);
    tcl_scan_b<<<1, 128, 0, stream>>>(bsum, nb);
    tcl_scan_c<<<(NN + 255) / 256, 256, 0, stream>>>(excl, bsum, roff, NN);
    tcl_edge<true><<<1024, 512, 0, stream>>>(atom, efeat, esh, eidx, b1, b2,
                                             w1tg, w2tg, tp, pos, roff, cnt, E);
    tcl_node2<<<1024, 256, 0, stream>>>(atom, tp, roff, cnt, out, statsrep, NN);
    tcl_collapse<<<1, 64, 0, stream>>>(statsrep, statsfin);
  } else {
    hipMemsetAsync(d_out, 0, (size_t)NN * 40 * sizeof(float), stream);
    tcl_edge<false><<<1024, 512, 0, stream>>>(atom, efeat, esh, eidx, b1, b2,
                                              w1tg, w2tg, out, pos, roff, cnt, E);
    tcl_node<<<256, 256, 0, stream>>>(atom, cnt, out, statsfin, NN);
  }
  tcl_norm<<<(int)(((long)NN * 40 + 255) / 256), 256, 0, stream>>>(out, statsfin, bnw, bnb, NN);
}

// Round 22
// 298.720 us; speedup vs baseline: 2.3377x; 1.0135x over previous
//
#include <hip/hip_runtime.h>
#include <hip/hip_bf16.h>

// TensorConvLayer: edge MLP (bf16 MFMA) -> tensor product (in-register) ->
// ticketed sorted-row emit (1 int atomic/edge) -> coalesced node gather -> BN.
//
// R21 -> R22 (single change): R21 green 303us (edge 229) -- LDS-tier fix
// confirmed. Remaining: 12M bank-conflict cycles (~8.5% + chain latency):
// row-major weight tile gives bank0 = 4*(l15+kg) mod 32 -> 8-way conflict
// on all 72 weight ds_read_b128/group. Fix: FRAGMENT-MAJOR layout
// tbl[mf][half][kg][l15][8] built in prep -> lane i reads byte i*16 of a
// contiguous 1KB chunk: sequential, zero-conflict. Pure permutation
// (arithmetic bit-identical); LDS 148 -> 134.5KB. Rest = green R21.

typedef __bf16 bf16_t;
typedef bf16_t bf16x8 __attribute__((ext_vector_type(8)));
typedef bf16_t bf16x4 __attribute__((ext_vector_type(4)));
typedef float  f32x4  __attribute__((ext_vector_type(4)));

#define NREP 32   // stats replicas

__device__ __forceinline__ bf16_t f2bf(float f) {
  unsigned u = __builtin_bit_cast(unsigned, f);
  u += 0x7fffu + ((u >> 16) & 1u);          // round-to-nearest-even
  unsigned short s = (unsigned short)(u >> 16);
  return __builtin_bit_cast(bf16_t, s);
}

#define MFMA16(a, b, c) __builtin_amdgcn_mfma_f32_16x16x32_bf16((a), (b), (c), 0, 0, 0)

// ---------------------------------------------------------------- zero ----
__global__ __launch_bounds__(256) void tcl_zero(
    int* __restrict__ cnt, int* __restrict__ pos, float* __restrict__ statsrep,
    float* __restrict__ statsfin, int NN)
{
  int t = blockIdx.x * 256 + threadIdx.x;
  if (t < NN) { cnt[t] = 0; pos[t] = 0; }
  if (t < NREP * 64) statsrep[t] = 0.f;
  if (t < 64) statsfin[t] = 0.f;
}

// ------------------------------------------------------- count + wprep ----
// Weights emitted FRAGMENT-MAJOR: elem t = ((((mf*2+half)*4+kg)*16)+l15)*8+e
// holds W[k][n] with n = 16*mf + l15, k = half*32 + kg*8 + e.
__global__ __launch_bounds__(256) void tcl_count(
    const int* __restrict__ eidx, const float* __restrict__ w1,
    const float* __restrict__ w2, unsigned short* __restrict__ w1tg,
    unsigned short* __restrict__ w2tg, int* __restrict__ cnt, int E)
{
  int t = blockIdx.x * 256 + threadIdx.x;
  if (t < E) atomicAdd(&cnt[eidx[E + t]], 1);
  if (t < 64 * 64) {
    int e = t & 7, l15 = (t >> 3) & 15, kg = (t >> 7) & 3, half = (t >> 9) & 1, mf = t >> 10;
    int n = 16 * mf + l15, k = half * 32 + kg * 8 + e;
    w1tg[t] = __builtin_bit_cast(unsigned short, f2bf(w1[k * 64 + n]));
  }
  if (t < 576 * 64) {
    int e = t & 7, l15 = (t >> 3) & 15, kg = (t >> 7) & 3, half = (t >> 9) & 1, mf = t >> 10;
    int n = 16 * mf + l15, k = half * 32 + kg * 8 + e;
    w2tg[t] = __builtin_bit_cast(unsigned short, f2bf(w2[k * 576 + n]));
  }
}

// ---------------------------------------------------------------- scan ----
__global__ __launch_bounds__(1024) void tcl_scan_a(
    const int* __restrict__ cnt, int* __restrict__ excl,
    int* __restrict__ bsum, int NN)
{
  __shared__ int sm[1024];
  int i = blockIdx.x * 1024 + threadIdx.x;
  int v = (i < NN) ? cnt[i] : 0;
  sm[threadIdx.x] = v;
  __syncthreads();
#pragma unroll
  for (int off = 1; off < 1024; off <<= 1) {
    int t = (threadIdx.x >= off) ? sm[threadIdx.x - off] : 0;
    __syncthreads();
    sm[threadIdx.x] += t;
    __syncthreads();
  }
  if (i < NN) excl[i] = sm[threadIdx.x] - v;
  if (threadIdx.x == 1023) bsum[blockIdx.x] = sm[threadIdx.x];
}

__global__ __launch_bounds__(128) void tcl_scan_b(int* __restrict__ bsum, int nb)
{
  __shared__ int sm[128];
  int t = threadIdx.x;
  int v = (t < nb) ? bsum[t] : 0;
  sm[t] = v;
  __syncthreads();
#pragma unroll
  for (int off = 1; off < 128; off <<= 1) {
    int u = (t >= off) ? sm[t - off] : 0;
    __syncthreads();
    sm[t] += u;
    __syncthreads();
  }
  if (t < nb) bsum[t] = sm[t] - v;
}

__global__ __launch_bounds__(256) void tcl_scan_c(
    const int* __restrict__ excl, const int* __restrict__ bsum,
    int* __restrict__ roff, int NN)
{
  int i = blockIdx.x * 256 + threadIdx.x;
  if (i < NN) roff[i] = excl[i] + bsum[i >> 10];
}

// ---------------------------------------------------------------- edge ----
// 512 threads = 8 autonomous waves, 16 edges each. Weights staged in LDS
// fragment-major (zero-conflict sequential ds_read_b128); one barrier.
template <bool SORTED>
__global__ __launch_bounds__(512) void tcl_edge(
    const float* __restrict__ atom, const float* __restrict__ efeat,
    const float* __restrict__ esh, const int* __restrict__ eidx,
    const float* __restrict__ b1, const float* __restrict__ b2,
    const unsigned short* __restrict__ w1tg, const unsigned short* __restrict__ w2tg,
    float* __restrict__ outbuf, int* __restrict__ pos,
    const int* __restrict__ roff, int* __restrict__ cnt, int E)
{
  // ~134.5KB LDS -> 1 block/CU.
  __shared__ __attribute__((aligned(16))) bf16_t w2l[576 * 64];
  __shared__ __attribute__((aligned(16))) bf16_t w1l[64 * 64];
  __shared__ __attribute__((aligned(16))) float  b2l[576];
  __shared__ __attribute__((aligned(16))) float  b1l[64];
  __shared__ __attribute__((aligned(16))) bf16_t hlds[8][16][72];
  __shared__ __attribute__((aligned(16))) float  xg[8][16][68];

  const int tid  = threadIdx.x;
  const int wv   = tid >> 6;      // wave 0..7 (independent after staging)
  const int lane = tid & 63;
  const int l15  = lane & 15;     // edge in group
  const int kg   = lane >> 4;     // K-slice 0..3
  const int kh   = kg >> 1;
  const int fo   = (l15 << 3);    // fragment elem offset within 128-chunk

  // ---- stage weights once per block (linear dword copy) ----
  {
    const unsigned* s2 = (const unsigned*)w2tg;
    unsigned* d2 = (unsigned*)w2l;
    for (int i = tid; i < 576 * 32; i += 512) d2[i] = s2[i];
    const unsigned* s1 = (const unsigned*)w1tg;
    unsigned* d1 = (unsigned*)w1l;
    for (int i = tid; i < 64 * 32; i += 512) d1[i] = s1[i];
    for (int i = tid; i < 576; i += 512) b2l[i] = b2[i];
    if (tid < 64) b1l[tid] = b1[tid];
  }
  __syncthreads();                 // the ONLY barrier

  const int ngr = (E + 15) >> 4;
  const int gw0 = blockIdx.x * 8 + wv;
  const int gstride = gridDim.x * 8;

  for (int g = gw0; g < ngr; g += gstride) {
    long ge = (long)g * 16 + l15;
    bool v = ge < E;

    // ---- A: efeat -> B-fragments direct from global (full K=64 row) ----
    bf16x8 Bf0, Bf1;
    {
      float4 a = {0,0,0,0}, b = a, c = a, d = a;
      if (v) {
        const float4* p = (const float4*)(efeat + ge * 64 + kg * 8);
        a = p[0]; b = p[1];
        const float4* q = (const float4*)(efeat + ge * 64 + 32 + kg * 8);
        c = q[0]; d = q[1];
      }
      Bf0[0]=f2bf(a.x); Bf0[1]=f2bf(a.y); Bf0[2]=f2bf(a.z); Bf0[3]=f2bf(a.w);
      Bf0[4]=f2bf(b.x); Bf0[5]=f2bf(b.y); Bf0[6]=f2bf(b.z); Bf0[7]=f2bf(b.w);
      Bf1[0]=f2bf(c.x); Bf1[1]=f2bf(c.y); Bf1[2]=f2bf(c.z); Bf1[3]=f2bf(c.w);
      Bf1[4]=f2bf(d.x); Bf1[5]=f2bf(d.y); Bf1[6]=f2bf(d.z); Bf1[7]=f2bf(d.w);
    }

    // ---- B: premultiplied TP coefficient table (work split by kg) ----
    //  [0:16) x0 | [16:40) x1*sh0*c11 | [40:48) (x1.sh1)*c10
    //  [48:64) x0*sh0*c00 | [64:67) sh1*c01
    if (v) {
      int dst = eidx[ge];
      const float* xr = atom + (long)dst * 40;
      const float inv_s2 = 0.70710678118654752f;
      if (kg == 0) {
        for (int i = 0; i < 16; ++i) xg[wv][l15][i] = xr[i];
      } else if (kg == 1) {
        float k11 = esh[ge * 4] * inv_s2 * 0.35355339059327378f;
        for (int t2 = 0; t2 < 24; ++t2) xg[wv][l15][16 + t2] = xr[16 + t2] * k11;
      } else if (kg == 2) {
        float s1x = esh[ge * 4 + 1], s1y = esh[ge * 4 + 2], s1z = esh[ge * 4 + 3];
        float k10 = inv_s2 * 0.20412414523193150f;
        for (int i = 0; i < 8; ++i) {
          float y = xr[16 + 3 * i] * s1x + xr[17 + 3 * i] * s1y + xr[18 + 3 * i] * s1z;
          xg[wv][l15][40 + i] = y * k10;
        }
        float ks = inv_s2 * 0.25f;
        xg[wv][l15][64] = s1x * ks;
        xg[wv][l15][65] = s1y * ks;
        xg[wv][l15][66] = s1z * ks;
      } else {
        float k0s = esh[ge * 4] * inv_s2 * 0.25f;
        for (int i = 0; i < 16; ++i) xg[wv][l15][48 + i] = xr[i] * k0s;
      }
    }

    // ---- C: GEMM1  h = relu(W1T . ef + b1); fragment-major LDS reads ----
    for (int mf = 0; mf < 4; ++mf) {
      bf16x8 a0 = *(const bf16x8*)(w1l + ((mf * 8 + kg) << 7) + fo);
      bf16x8 a1 = *(const bf16x8*)(w1l + ((mf * 8 + 4 + kg) << 7) + fo);
      f32x4 acc = {0.f, 0.f, 0.f, 0.f};
      acc = MFMA16(a0, Bf0, acc);
      acc = MFMA16(a1, Bf1, acc);
      int j0 = 16 * mf + 4 * kg;   // C/D: col=lane&15 (edge), row=(lane>>4)*4+r
      bf16x4 hv;
#pragma unroll
      for (int r = 0; r < 4; ++r) {
        float x = acc[r] + b1l[j0 + r];
        x = x > 0.f ? x : 0.f;
        hv[r] = f2bf(x);
      }
      *(bf16x4*)&hlds[wv][l15][j0] = hv;
    }

    // ---- D: re-read h as B-fragments (same wave; lgkmcnt ordering) ----
    bf16x8 Bh0 = *(const bf16x8*)&hlds[wv][l15][kg * 8];
    bf16x8 Bh1 = *(const bf16x8*)&hlds[wv][l15][32 + kg * 8];
    float s0 = xg[wv][l15][64], s1 = xg[wv][l15][65], s2 = xg[wv][l15][66];

    // ---- E: GEMM2 + TP; fragment-major zero-conflict weight reads ----
    float o0[4] = {};        // out0 slice j = 4*kg + r (complete per lane)
    float o1[4][3] = {};     // out1 slice j = 4*(kg&1) + r (partial: this kh)

    for (int mf = 0; mf < 16; ++mf) {          // w00: i=mf, j=4*kg+r
      bf16x8 a0 = *(const bf16x8*)(w2l + ((mf * 8 + kg) << 7) + fo);
      bf16x8 a1 = *(const bf16x8*)(w2l + ((mf * 8 + 4 + kg) << 7) + fo);
      f32x4 bv = *(const f32x4*)&b2l[16 * mf + 4 * kg];
      f32x4 acc = {0.f, 0.f, 0.f, 0.f};
      acc = MFMA16(a0, Bh0, acc);
      acc = MFMA16(a1, Bh1, acc);
      float cA = xg[wv][l15][48 + mf];
#pragma unroll
      for (int r = 0; r < 4; ++r) o0[r] += (acc[r] + bv[r]) * cA;
    }
    for (int mf = 16; mf < 20; ++mf) {         // w11: i=2*(mf-16)+kh, j=4*(kg&1)+r
      bf16x8 a0 = *(const bf16x8*)(w2l + ((mf * 8 + kg) << 7) + fo);
      bf16x8 a1 = *(const bf16x8*)(w2l + ((mf * 8 + 4 + kg) << 7) + fo);
      f32x4 bv = *(const f32x4*)&b2l[16 * mf + 4 * kg];
      f32x4 acc = {0.f, 0.f, 0.f, 0.f};
      acc = MFMA16(a0, Bh0, acc);
      acc = MFMA16(a1, Bh1, acc);
      int i = 2 * (mf - 16) + kh;
      float c0 = xg[wv][l15][16 + 3 * i], c1 = xg[wv][l15][17 + 3 * i], c2 = xg[wv][l15][18 + 3 * i];
#pragma unroll
      for (int r = 0; r < 4; ++r) {
        float wA = acc[r] + bv[r];
        o1[r][0] += wA * c0; o1[r][1] += wA * c1; o1[r][2] += wA * c2;
      }
    }
    for (int mf = 20; mf < 28; ++mf) {         // w01: i=2*(mf-20)+kh, j=4*(kg&1)+r
      bf16x8 a0 = *(const bf16x8*)(w2l + ((mf * 8 + kg) << 7) + fo);
      bf16x8 a1 = *(const bf16x8*)(w2l + ((mf * 8 + 4 + kg) << 7) + fo);
      f32x4 bv = *(const f32x4*)&b2l[16 * mf + 4 * kg];
      f32x4 acc = {0.f, 0.f, 0.f, 0.f};
      acc = MFMA16(a0, Bh0, acc);
      acc = MFMA16(a1, Bh1, acc);
      int i = 2 * (mf - 20) + kh;
      float xA = xg[wv][l15][i];
#pragma unroll
      for (int r = 0; r < 4; ++r) {
        float tA = (acc[r] + bv[r]) * xA;
        o1[r][0] += tA * s0; o1[r][1] += tA * s1; o1[r][2] += tA * s2;
      }
    }
    for (int mf = 28; mf < 36; ++mf) {         // w10: i=mf-28, j=4*kg+r
      bf16x8 a0 = *(const bf16x8*)(w2l + ((mf * 8 + kg) << 7) + fo);
      bf16x8 a1 = *(const bf16x8*)(w2l + ((mf * 8 + 4 + kg) << 7) + fo);
      f32x4 bv = *(const f32x4*)&b2l[16 * mf + 4 * kg];
      f32x4 acc = {0.f, 0.f, 0.f, 0.f};
      acc = MFMA16(a0, Bh0, acc);
      acc = MFMA16(a1, Bh1, acc);
      float cA = xg[wv][l15][40 + mf - 28];
#pragma unroll
      for (int r = 0; r < 4; ++r) o0[r] += (acc[r] + bv[r]) * cA;
    }

    // fold kh pairs (lane^32: kg<->kg^2, same l15); lanes kg<2 hold full o1
    float o1f[4][3];
#pragma unroll
    for (int r = 0; r < 4; ++r)
#pragma unroll
      for (int c = 0; c < 3; ++c)
        o1f[r][c] = o1[r][c] + __shfl_xor(o1[r][c], 32);

    // ---- F: emit ----
    if (SORTED) {
      int dstrow = 0;
      if (v && kg == 0) {
        int src = eidx[E + ge];
        dstrow = roff[src] + atomicAdd(&pos[src], 1);
      }
      dstrow = __shfl(dstrow, l15);      // lane l15 holds kg==0's ticket
      if (v) {
        float* orow = outbuf + (long)dstrow * 40;
        f32x4 v0 = {o0[0], o0[1], o0[2], o0[3]};
        *(f32x4*)(orow + 4 * kg) = v0;
        if (kg < 2) {
          f32x4 u0 = {o1f[0][0], o1f[0][1], o1f[0][2], o1f[1][0]};
          f32x4 u1 = {o1f[1][1], o1f[1][2], o1f[2][0], o1f[2][1]};
          f32x4 u2 = {o1f[2][2], o1f[3][0], o1f[3][1], o1f[3][2]};
          float* ob = orow + 16 + 12 * kg;
          *(f32x4*)(ob + 0) = u0;
          *(f32x4*)(ob + 4) = u1;
          *(f32x4*)(ob + 8) = u2;
        }
      }
    } else {
      if (v) {
        int src = eidx[E + ge];
        float* srow = outbuf + (long)src * 40;
#pragma unroll
        for (int r = 0; r < 4; ++r) unsafeAtomicAdd(&srow[4 * kg + r], o0[r]);
        if (kg < 2) {
          int j1 = 4 * kg;
#pragma unroll
          for (int r = 0; r < 4; ++r)
#pragma unroll
            for (int c = 0; c < 3; ++c)
              unsafeAtomicAdd(&srow[16 + 3 * (j1 + r) + c], o1f[r][c]);
        }
      }
    }
  }
}

// -------------------------------------------------------- node (gather) ----
// stats atomics striped over NREP replicas (contention /32) + in-wave 3:1
// vsq fold (8 atomics instead of 24 for v channels).
__global__ __launch_bounds__(256) void tcl_node2(
    const float* __restrict__ atom, const float* __restrict__ tp,
    const int* __restrict__ roff, const int* __restrict__ cnt,
    float* __restrict__ out, float* __restrict__ statsrep, int NN)
{
  int lane = threadIdx.x & 63;
  int gw = blockIdx.x * 4 + (threadIdx.x >> 6);
  int stride = gridDim.x * 4;
  float ssum = 0.f, ssq = 0.f, vsq = 0.f;
  for (int n = gw; n < NN; n += stride) {
    int deg = cnt[n];
    long base = roff[n];
    if (lane < 40) {
      float acc = 0.f;
      for (int d = 0; d < deg; ++d) acc += tp[(base + d) * 40 + lane];
      float c = deg > 0 ? (float)deg : 1.f;
      long idx = (long)n * 40 + lane;
      float o = acc / c + atom[idx];
      out[idx] = o;
      if (lane < 16) { ssum += o; ssq += o * o; }
      else           { vsq += o * o; }
    }
  }
  float* srep = statsrep + (long)(blockIdx.x & (NREP - 1)) * 64;
  // fold 3 vector components in-wave: lane 16+3m collects 16+3m+1, 16+3m+2
  float va = __shfl(vsq, lane + 1);
  float vb = __shfl(vsq, lane + 2);
  if (lane < 16) {
    unsafeAtomicAdd(&srep[lane], ssum);
    unsafeAtomicAdd(&srep[16 + lane], ssq);
  } else if (lane < 40 && (lane - 16) % 3 == 0) {
    unsafeAtomicAdd(&srep[32 + (lane - 16) / 3], (vsq + va) + vb);
  }
}

// ------------------------------------------------------------ collapse ----
__global__ __launch_bounds__(64) void tcl_collapse(
    const float* __restrict__ statsrep, float* __restrict__ statsfin)
{
  int c = threadIdx.x;
  float s = 0.f;
  for (int r = 0; r < NREP; ++r) s += statsrep[(long)r * 64 + c];
  statsfin[c] = s;
}

// ---------------------------------------------------- node (atomic path) ----
__global__ __launch_bounds__(256) void tcl_node(
    const float* __restrict__ atom, const int* __restrict__ cnt,
    float* __restrict__ out, float* __restrict__ stats, int NN)
{
  int lane = threadIdx.x & 63;
  int gw = blockIdx.x * 4 + (threadIdx.x >> 6);
  int stride = gridDim.x * 4;
  float ssum = 0.f, ssq = 0.f, vsq = 0.f;
  for (int r = gw; r < NN; r += stride) {
    float c = (float)cnt[r];
    c = c > 1.f ? c : 1.f;
    if (lane < 40) {
      long idx = (long)r * 40 + lane;
      float o = out[idx] / c + atom[idx];
      out[idx] = o;
      if (lane < 16) { ssum += o; ssq += o * o; }
      else           { vsq += o * o; }
    }
  }
  if (lane < 16) {
    unsafeAtomicAdd(&stats[lane], ssum);
    unsafeAtomicAdd(&stats[16 + lane], ssq);
  } else if (lane < 40) {
    unsafeAtomicAdd(&stats[32 + (lane - 16) / 3], vsq);
  }
}

// ---------------------------------------------------------------- norm ----
__global__ __launch_bounds__(256) void tcl_norm(
    float* __restrict__ out, const float* __restrict__ stats,
    const float* __restrict__ bnw, const float* __restrict__ bnb, int NN)
{
  long idx = (long)blockIdx.x * 256 + threadIdx.x;
  long tot = (long)NN * 40;
  if (idx >= tot) return;
  int c = (int)(idx % 40);
  float o = out[idx];
  float invN = 1.0f / (float)NN;
  if (c < 16) {
    float mean = stats[c] * invN;
    float var  = stats[16 + c] * invN - mean * mean;
    float rs   = rsqrtf(var + 1e-5f);
    o = (o - mean) * rs * bnw[c] + bnb[c];
  } else {
    int m = (c - 16) / 3;
    float vn = stats[32 + m] * invN * (1.0f / 3.0f);
    float rs = rsqrtf(vn + 1e-5f);
    o = o * rs * bnw[16 + m];
  }
  out[idx] = o;
}

// -------------------------------------------------------------- launch ----
extern "C" void kernel_launch(void* const* d_in, const int* in_sizes, int n_in,
                              void* d_out, int out_size, void* d_ws, size_t ws_size,
                              hipStream_t stream)
{
  const float* atom  = (const float*)d_in[0];
  const float* efeat = (const float*)d_in[1];
  const float* esh   = (const float*)d_in[2];
  const int*   eidx  = (const int*)d_in[3];
  const float* w1    = (const float*)d_in[4];
  const float* b1    = (const float*)d_in[5];
  const float* w2    = (const float*)d_in[6];
  const float* b2    = (const float*)d_in[7];
  const float* bnw   = (const float*)d_in[8];
  const float* bnb   = (const float*)d_in[9];
  int E  = in_sizes[3] / 2;
  int NN = in_sizes[0] / 40;
  float* out = (float*)d_out;

  // workspace layout (~81.7MB for E=500k, NN=100k; proven fit in R2/R17)
  size_t off = 0;
  auto align256 = [&](size_t o) { return (o + 255) & ~(size_t)255; };
  int* cnt = (int*)d_ws;                                   off += (size_t)NN * 4;
  off = align256(off);
  int* pos = (int*)((char*)d_ws + off);                    off += (size_t)NN * 4;
  off = align256(off);
  int* excl = (int*)((char*)d_ws + off);                   off += (size_t)NN * 4;
  off = align256(off);
  int* bsum = (int*)((char*)d_ws + off);                   off += 128 * 4;
  off = align256(off);
  int* roff = (int*)((char*)d_ws + off);                   off += (size_t)NN * 4;
  off = align256(off);
  float* statsrep = (float*)((char*)d_ws + off);           off += (size_t)NREP * 64 * 4;
  off = align256(off);
  float* statsfin = (float*)((char*)d_ws + off);           off += 64 * 4;
  off = align256(off);
  unsigned short* w1tg = (unsigned short*)((char*)d_ws + off); off += 64 * 64 * 2;
  off = align256(off);
  unsigned short* w2tg = (unsigned short*)((char*)d_ws + off); off += 576 * 64 * 2;
  off = align256(off);
  float* tp = (float*)((char*)d_ws + off);
  size_t need = off + (size_t)E * 40 * 4;

  int nb = (NN + 1023) / 1024;   // scan chunks (<=128)
  bool sorted = (ws_size >= need) && (nb <= 128);

  tcl_zero<<<(NN + 255) / 256, 256, 0, stream>>>(cnt, pos, statsrep, statsfin, NN);
  tcl_count<<<(E + 255) / 256, 256, 0, stream>>>(eidx, w1, w2, w1tg, w2tg, cnt, E);

  if (sorted) {
    tcl_scan_a<<<nb, 1024, 0, stream>>>(cnt, excl, bsum, NN);
    tcl_scan_b<<<1, 128, 0, stream>>>(bsum, nb);
    tcl_scan_c<<<(NN + 255) / 256, 256, 0, stream>>>(excl, bsum, roff, NN);
    tcl_edge<true><<<1024, 512, 0, stream>>>(atom, efeat, esh, eidx, b1, b2,
                                             w1tg, w2tg, tp, pos, roff, cnt, E);
    tcl_node2<<<1024, 256, 0, stream>>>(atom, tp, roff, cnt, out, statsrep, NN);
    tcl_collapse<<<1, 64, 0, stream>>>(statsrep, statsfin);
  } else {
    hipMemsetAsync(d_out, 0, (size_t)NN * 40 * sizeof(float), stream);
    tcl_edge<false><<<1024, 512, 0, stream>>>(atom, efeat, esh, eidx, b1, b2,
                                              w1tg, w2tg, out, pos, roff, cnt, E);
    tcl_node<<<256, 256, 0, stream>>>(atom, cnt, out, statsfin, NN);
  }
  tcl_norm<<<(int)(((long)NN * 40 + 255) / 256), 256, 0, stream>>>(out, statsfin, bnw, bnb, NN);
}